// Round 10
// baseline (498.316 us; speedup 1.0000x reference)
//
#include <hip/hip_runtime.h>
#include <math.h>

#define FDIM 32
#define NBASIS 8
#define TBL 2048  // radial table points
#define BINW 4096 // edges per bin_dst window
#define DCAP 4096 // sort_bucket LDS record capacity
#define GSPLIT 8  // gather WGs per src bucket

constexpr float RCUT_C = 20.0f;
constexpr float EV2KJ_C = 96.4853f;
constexpr float NM2A_C = 10.0f;

typedef float f32x4 __attribute__((ext_vector_type(4)));

__device__ __forceinline__ float sigmoidf_(float z) { return 1.0f / (1.0f + __expf(-z)); }

__device__ __forceinline__ unsigned int pk2_(float a, float b) {
    unsigned short lo = __builtin_bit_cast(unsigned short, (_Float16)a);
    unsigned short hi = __builtin_bit_cast(unsigned short, (_Float16)b);
    return (unsigned int)lo | ((unsigned int)hi << 16);
}
__device__ __forceinline__ float lo16_(unsigned int v) {
    return (float)__builtin_bit_cast(_Float16, (unsigned short)(v & 0xffffu));
}
__device__ __forceinline__ float hi16_(unsigned int v) {
    return (float)__builtin_bit_cast(_Float16, (unsigned short)(v >> 16));
}

// ---------------- bucketed CSR build (no N-wide scans, no random scatter) ----------------
__global__ __launch_bounds__(256) void hist_buckets(
    const int* __restrict__ eidx, int* __restrict__ dbcnt, int* __restrict__ sbcnt,
    int E, int dsh, int ssh, int nbd, int nbs)
{
    __shared__ int ld[512];
    __shared__ int ls[64];
    for (int i = threadIdx.x; i < nbd; i += 256) ld[i] = 0;
    for (int i = threadIdx.x; i < nbs; i += 256) ls[i] = 0;
    __syncthreads();
    for (int e = blockIdx.x * 256 + threadIdx.x; e < E; e += gridDim.x * 256) {
        int s = eidx[e];
        int d = eidx[E + e];
        atomicAdd(&ld[d >> dsh], 1);
        atomicAdd(&ls[s >> ssh], 1);
    }
    __syncthreads();
    for (int i = threadIdx.x; i < nbd; i += 256) if (ld[i]) atomicAdd(&dbcnt[i], ld[i]);
    for (int i = threadIdx.x; i < nbs; i += 256) if (ls[i]) atomicAdd(&sbcnt[i], ls[i]);
}

__global__ __launch_bounds__(512) void scan_bases(
    const int* __restrict__ dbcnt, const int* __restrict__ sbcnt,
    int* __restrict__ dbbase, int* __restrict__ sbbase, int nbd, int nbs)
{
    __shared__ int buf[512];
    const int t = threadIdx.x;
    int v = (t < nbd) ? dbcnt[t] : 0;
    buf[t] = v;
    __syncthreads();
    for (int off = 1; off < 512; off <<= 1) {
        int u = (t >= off) ? buf[t - off] : 0;
        __syncthreads();
        buf[t] += u;
        __syncthreads();
    }
    if (t < nbd) dbbase[t] = buf[t] - v;
    if (t == 511) dbbase[nbd] = buf[511];
    __syncthreads();
    int v2 = (t < nbs) ? sbcnt[t] : 0;
    buf[t] = v2;
    __syncthreads();
    for (int off = 1; off < 512; off <<= 1) {
        int u = (t >= off) ? buf[t - off] : 0;
        __syncthreads();
        buf[t] += u;
        __syncthreads();
    }
    if (t < nbs) sbbase[t] = buf[t] - v2;
    if (t == 511) sbbase[nbs] = buf[511];
}

__global__ __launch_bounds__(256) void bin_dst(
    const int* __restrict__ eidx, const int* __restrict__ dbbase,
    int* __restrict__ dbcur, int2* __restrict__ order_sd,
    int E, int dsh, int nbd)
{
    __shared__ int2 rec[BINW];          // 32 KB
    __shared__ int lcnt[512], lbase[512], lofs[512];
    const int t = threadIdx.x;
    const int w0 = blockIdx.x * BINW;
    const int n = min(BINW, E - w0);
    if (n <= 0) return;
    for (int i = t; i < nbd; i += 256) lcnt[i] = 0;
    __syncthreads();
    for (int i = t; i < n; i += 256) {
        int e = w0 + i;
        int2 r = make_int2(eidx[e], eidx[E + e]);
        rec[i] = r;
        atomicAdd(&lcnt[r.y >> dsh], 1);
    }
    __syncthreads();
    for (int i = t; i < nbd; i += 256) {
        int c = lcnt[i];
        lbase[i] = c ? atomicAdd(&dbcur[i], c) : 0;
        lofs[i] = 0;
    }
    __syncthreads();
    for (int i = t; i < n; i += 256) {
        int2 r = rec[i];
        int b = r.y >> dsh;
        int pos = lbase[b] + atomicAdd(&lofs[b], 1);
        order_sd[dbbase[b] + pos] = r;
    }
}

__global__ __launch_bounds__(256) void sort_bucket(
    int2* __restrict__ order_sd, const int* __restrict__ dbbase,
    int* __restrict__ sbcur, const int* __restrict__ sbbase,
    int2* __restrict__ srcbin, int dsh, int ssh)
{
    __shared__ int2 rec[DCAP];          // 32 KB
    __shared__ int c128[128], o128[128];
    __shared__ int sc[64], sbres[64], so[64];
    const int b = blockIdx.x, t = threadIdx.x;
    const int base = dbbase[b];
    const int cnt = dbbase[b + 1] - base;
    const bool dosort = (dsh <= 7);
    const int kmask = (1 << dsh) - 1;

    for (int start = 0; start < cnt; start += DCAP) {
        const int n = min(DCAP, cnt - start);
        if (t < 128) c128[t] = 0;
        if (t < 64) sc[t] = 0;
        __syncthreads();
        for (int i = t; i < n; i += 256) {
            int2 r = order_sd[base + start + i];
            rec[i] = r;
            if (dosort) atomicAdd(&c128[r.y & kmask], 1);
            atomicAdd(&sc[r.x >> ssh], 1);
        }
        __syncthreads();
        int v0 = (t < 128) ? c128[t] : 0;
        __syncthreads();
        for (int off = 1; off < 128; off <<= 1) {
            int u = (t < 128 && t >= off) ? c128[t - off] : 0;
            __syncthreads();
            if (t < 128) c128[t] += u;
            __syncthreads();
        }
        if (t < 128) o128[t] = c128[t] - v0;
        if (t < 64) {
            int c = sc[t];
            sbres[t] = c ? atomicAdd(&sbcur[t], c) : 0;
            so[t] = 0;
        }
        __syncthreads();
        for (int i = t; i < n; i += 256) {
            int2 r = rec[i];
            int p;
            if (dosort) {
                int pos = atomicAdd(&o128[r.y & kmask], 1);
                p = base + start + pos;
                order_sd[p] = r;
            } else {
                p = base + start + i;
            }
            int sb2 = r.x >> ssh;
            int slot = sbres[sb2] + atomicAdd(&so[sb2], 1);
            srcbin[sbbase[sb2] + slot] = make_int2(r.x, p);
        }
        __syncthreads();
    }
}

// ---------------- radial table build: rtab[i][{q[64], t[64]}] as f(x = i/(TBL-1)) ----------
// q = silu(basis@Wr1 + b) @ Wr2 ; t = (silu'(z) * (dbasis@Wr1)) @ Wr2 ; double-precision
// basis/dbasis (the 1/r singular parts cancel analytically; limits used at i=0).
__global__ __launch_bounds__(64) void build_rtab(
    const float* __restrict__ Wr1, const float* __restrict__ br1,
    const float* __restrict__ Wr2, float* __restrict__ rtab)
{
    __shared__ float sil[32], tfv[32];
    const int i = blockIdx.x;
    const int t = threadIdx.x;
    const double x = (double)i / (double)(TBL - 1);
    const double r = x * (double)RCUT_C;
    float bas[NBASIS], dbs[NBASIS];
    #pragma unroll
    for (int n = 0; n < NBASIS; n++) {
        double pn = M_PI * (double)(n + 1);
        if (i == 0) {
            bas[n] = (float)(pn / (double)RCUT_C);
            dbs[n] = 0.0f;
        } else {
            double a = pn * x;
            double s = sin(a), c = cos(a);
            bas[n] = (float)(s / r);
            dbs[n] = (float)((pn / (double)RCUT_C) * c / r - s / (r * r));
        }
    }
    if (t < 32) {
        float z = br1[t], dz = 0.0f;
        #pragma unroll
        for (int k = 0; k < NBASIS; k++) {
            z  += bas[k] * Wr1[k * FDIM + t];
            dz += dbs[k] * Wr1[k * FDIM + t];
        }
        float sg = sigmoidf_(z);
        sil[t] = z * sg;
        tfv[t] = (sg * (1.0f + z * (1.0f - sg))) * dz;
    }
    __syncthreads();
    float q = 0.0f, tv = 0.0f;
    #pragma unroll
    for (int j = 0; j < 32; j++) {
        float w2 = Wr2[j * 64 + t];
        q  += sil[j] * w2;
        tv += tfv[j] * w2;
    }
    rtab[(size_t)i * 128 + t]      = q;
    rtab[(size_t)i * 128 + 64 + t] = tv;
}

// ---------------- edge forward (tabulated): geometry + table lerp + fold; run-merge ------
// LDS plane Df[ch(64)][edge(32)] f32, pad 33: writes (lane=edge) and reads (lane=ch)
// both conflict-free. No MFMA, no basis, no silu.
__global__ __launch_bounds__(256) void edge_fwd_tab(
    const float* __restrict__ pos, const int* __restrict__ types,
    const int2* __restrict__ order_sd, const float* __restrict__ rtab,
    const float* __restrict__ temb,
    float* __restrict__ s_acc, float* __restrict__ v_acc, int E)
{
    __shared__ float sDf[4][64 * 33];      // 8448 B/wave
    __shared__ float sSt[4][32][4];        // env, rhx, rhy, rhz
    __shared__ int sTy[4][32];
    __shared__ int sKey[4][32];
    __shared__ int sIx[4][32];
    __shared__ float sFr[4][32];
    __shared__ float sTemb[96];

    const int lane = threadIdx.x & 63;
    const int l32 = threadIdx.x & 31;
    const int w = threadIdx.x >> 6;
    const int gbase = blockIdx.x * 128 + w * 32;

    for (int i = threadIdx.x; i < 96; i += 256) sTemb[i] = temb[i];
    __syncthreads();

    // ---- phase 0: geometry (lanes 0..31), table coords ----
    if (lane < 32) {
        const int m = l32;
        const int p = gbase + m;
        const bool vld = (p < E);
        int2 sd = vld ? order_sd[p] : make_int2(0, 0);
        float rx = (pos[sd.y * 3 + 0] - pos[sd.x * 3 + 0]) * NM2A_C;
        float ry = (pos[sd.y * 3 + 1] - pos[sd.x * 3 + 1]) * NM2A_C;
        float rz = (pos[sd.y * 3 + 2] - pos[sd.x * 3 + 2]) * NM2A_C;
        float r2 = rx * rx + ry * ry + rz * rz + 1e-12f;
        float r = sqrtf(r2);
        float rinv = 1.0f / r;
        float x = r * (1.0f / RCUT_C);
        float x2 = x * x, x4 = x2 * x2, x6 = x4 * x2, x7 = x6 * x, x8 = x6 * x2;
        float env = (x < 1.0f) ? (1.0f - 28.0f * x6 + 48.0f * x7 - 21.0f * x8) : 0.0f;
        float xs = x * (float)(TBL - 1);
        int ti = min((int)xs, TBL - 2);
        sIx[w][m] = ti;
        sFr[w][m] = xs - (float)ti;
        sSt[w][m][0] = env;
        sSt[w][m][1] = rx * rinv;
        sSt[w][m][2] = ry * rinv;
        sSt[w][m][3] = rz * rinv;
        sTy[w][m] = types[sd.x];
        sKey[w][m] = vld ? sd.y : -1;
    }

    // ---- stage B: all lanes; 2 lanes/edge; lerp q-half, fold hs*env, write plane ----
    {
        const int m = lane >> 1, h = lane & 1;
        const int ti = sIx[w][m];
        const float fr = sFr[w][m];
        const float env = sSt[w][m][0];
        const int ty = sTy[w][m];
        const float* r0 = rtab + (size_t)ti * 128 + h * 32;
        const float* r1 = r0 + 128;
        float* Dc = &sDf[w][0];
        const int cb = h * 32;
        #pragma unroll
        for (int c4 = 0; c4 < 8; c4++) {
            f32x4 a = *(const f32x4*)(r0 + c4 * 4);
            f32x4 b = *(const f32x4*)(r1 + c4 * 4);
            #pragma unroll
            for (int j = 0; j < 4; j++) {
                int c = c4 * 4 + j;
                float v = (a[j] + fr * (b[j] - a[j])) * env * sTemb[ty * 32 + c];
                Dc[(cb + c) * 33 + m] = v;
            }
        }
    }

    // ---- epilogue: full-wave contiguous run-merge over 32 edges; 2 atomics/flush ----
    {
        const float* Dc = &sDf[w][0];
        const bool loHalf = (lane < 32);
        const int mmax = min(32, E - gbase);
        int runKey = -1;
        float a0 = 0.f, a1 = 0.f;
        for (int m = 0; m < mmax; m++) {
            int k = sKey[w][m];
            if (k != runKey) {
                if (runKey >= 0) {
                    float* p0 = loHalf ? &s_acc[(size_t)runKey * 32 + l32]
                                       : &v_acc[(size_t)runKey * 96 + l32];
                    float* p1 = loHalf ? &v_acc[(size_t)runKey * 96 + 32 + l32]
                                       : &v_acc[(size_t)runKey * 96 + 64 + l32];
                    unsafeAtomicAdd(p0, a0);
                    unsafeAtomicAdd(p1, a1);
                }
                runKey = k;
                a0 = a1 = 0.f;
            }
            float hi = Dc[(32 + l32) * 33 + m];
            float lo = Dc[l32 * 33 + m];
            float rA = sSt[w][m][1], rY = sSt[w][m][2], rZ = sSt[w][m][3];
            a0 += loHalf ? lo : hi * rA;
            a1 += hi * (loHalf ? rY : rZ);
        }
        if (runKey >= 0) {
            float* p0 = loHalf ? &s_acc[(size_t)runKey * 32 + l32]
                               : &v_acc[(size_t)runKey * 96 + l32];
            float* p1 = loHalf ? &v_acc[(size_t)runKey * 96 + 32 + l32]
                               : &v_acc[(size_t)runKey * 96 + 64 + l32];
            unsafeAtomicAdd(p0, a0);
            unsafeAtomicAdd(p1, a1);
        }
    }
}

// -------- atom MLP v3: one atom per thread, phased register lifetimes (no spill) ----
__global__ __launch_bounds__(64) void atom_mlp(
    const int* __restrict__ types, const float* __restrict__ temb,
    const float* __restrict__ Wself, const float* __restrict__ Wo1,
    const float* __restrict__ bo1, const float* __restrict__ Wo2,
    const float* __restrict__ s_acc, const float* __restrict__ v_acc,
    float* __restrict__ g_all, float* __restrict__ out, int N)
{
    __shared__ __align__(16) float sWs[FDIM * FDIM];        // 32x32
    __shared__ __align__(16) float sWo1[2 * FDIM * FDIM];   // 64x32
    __shared__ __align__(16) float sb[FDIM], sW2o[FDIM], sTE[96];
    const int t = threadIdx.x;
    for (int i = t; i < FDIM * FDIM; i += 64) sWs[i] = Wself[i];
    for (int i = t; i < 2 * FDIM * FDIM; i += 64) sWo1[i] = Wo1[i];
    if (t < FDIM) { sb[t] = bo1[t]; sW2o[t] = Wo2[t]; }
    for (int i = t; i < 96; i += 64) sTE[i] = temb[i];
    __syncthreads();

    int a = blockIdx.x * 64 + t;
    const bool valid = (a < N);
    if (!valid) a = 0;
    const int ty = types[a];

    float u[32];                       // becomes gu in phase C
    {
        float row[32];
        #pragma unroll
        for (int j = 0; j < 32; j++) row[j] = sTE[ty * FDIM + j];
        {
            float s_[32];
            #pragma unroll
            for (int q = 0; q < 8; q++) {
                float4 v = *(const float4*)&s_acc[(size_t)a * FDIM + q * 4];
                s_[q * 4 + 0] = v.x; s_[q * 4 + 1] = v.y;
                s_[q * 4 + 2] = v.z; s_[q * 4 + 3] = v.w;
            }
            #pragma unroll
            for (int k = 0; k < 32; k++) {
                float sk = s_[k];
                #pragma unroll
                for (int q = 0; q < 8; q++) {
                    float4 wv = *(const float4*)&sWs[k * 32 + q * 4];
                    row[q * 4 + 0] += sk * wv.x; row[q * 4 + 1] += sk * wv.y;
                    row[q * 4 + 2] += sk * wv.z; row[q * 4 + 3] += sk * wv.w;
                }
            }
        }
        #pragma unroll
        for (int j = 0; j < 32; j++) u[j] = sb[j];
        #pragma unroll
        for (int k = 0; k < 32; k++) {
            float rk = row[k];
            #pragma unroll
            for (int q = 0; q < 8; q++) {
                float4 w1 = *(const float4*)&sWo1[k * 32 + q * 4];
                u[q * 4 + 0] += rk * w1.x; u[q * 4 + 1] += rk * w1.y;
                u[q * 4 + 2] += rk * w1.z; u[q * 4 + 3] += rk * w1.w;
            }
        }
    }

    float vn[32];
    #pragma unroll
    for (int q = 0; q < 8; q++) {
        float4 x4 = *(const float4*)&v_acc[(size_t)a * 96 +      q * 4];
        float4 y4 = *(const float4*)&v_acc[(size_t)a * 96 + 32 + q * 4];
        float4 z4 = *(const float4*)&v_acc[(size_t)a * 96 + 64 + q * 4];
        vn[q * 4 + 0] = sqrtf(x4.x * x4.x + y4.x * y4.x + z4.x * z4.x + 1e-12f);
        vn[q * 4 + 1] = sqrtf(x4.y * x4.y + y4.y * y4.y + z4.y * z4.y + 1e-12f);
        vn[q * 4 + 2] = sqrtf(x4.z * x4.z + y4.z * y4.z + z4.z * z4.z + 1e-12f);
        vn[q * 4 + 3] = sqrtf(x4.w * x4.w + y4.w * y4.w + z4.w * z4.w + 1e-12f);
    }
    #pragma unroll
    for (int k = 0; k < 32; k++) {
        float vk = vn[k];
        #pragma unroll
        for (int q = 0; q < 8; q++) {
            float4 w2 = *(const float4*)&sWo1[(k + 32) * 32 + q * 4];
            u[q * 4 + 0] += vk * w2.x; u[q * 4 + 1] += vk * w2.y;
            u[q * 4 + 2] += vk * w2.z; u[q * 4 + 3] += vk * w2.w;
        }
    }

    {
        float pa = 0.0f;
        #pragma unroll
        for (int j = 0; j < 32; j++) {
            float z = u[j];
            float sg = sigmoidf_(z);
            pa += z * sg * sW2o[j];
            u[j] = sW2o[j] * (sg * (1.0f + z * (1.0f - sg)));   // gu
        }
        if (!valid) pa = 0.0f;
        #pragma unroll
        for (int m = 32; m; m >>= 1) pa += __shfl_xor(pa, m, 64);
        if (t == 0) unsafeAtomicAdd(out, pa * EV2KJ_C);
    }

    float sc[32];
    #pragma unroll
    for (int j = 0; j < 32; j++) {
        float av = 0.f;
        #pragma unroll
        for (int q = 0; q < 8; q++) {
            float4 w2 = *(const float4*)&sWo1[(j + 32) * 32 + q * 4];
            av += u[q * 4 + 0] * w2.x + u[q * 4 + 1] * w2.y
                + u[q * 4 + 2] * w2.z + u[q * 4 + 3] * w2.w;
        }
        sc[j] = av / vn[j];
    }

    float gfr[32];
    #pragma unroll
    for (int j = 0; j < 32; j++) {
        float ar = 0.f;
        #pragma unroll
        for (int q = 0; q < 8; q++) {
            float4 w1 = *(const float4*)&sWo1[j * 32 + q * 4];
            ar += u[q * 4 + 0] * w1.x + u[q * 4 + 1] * w1.y
                + u[q * 4 + 2] * w1.z + u[q * 4 + 3] * w1.w;
        }
        gfr[j] = ar;
    }

    float gs[32];
    #pragma unroll
    for (int j = 0; j < 32; j++) {
        float acc = 0.f;
        #pragma unroll
        for (int q = 0; q < 8; q++) {
            float4 wv = *(const float4*)&sWs[j * 32 + q * 4];
            acc += gfr[q * 4 + 0] * wv.x + gfr[q * 4 + 1] * wv.y
                 + gfr[q * 4 + 2] * wv.z + gfr[q * 4 + 3] * wv.w;
        }
        gs[j] = acc;
    }

    if (valid) {
        #pragma unroll
        for (int q = 0; q < 8; q++) {
            float4 x4 = *(const float4*)&v_acc[(size_t)a * 96 +      q * 4];
            float4 y4 = *(const float4*)&v_acc[(size_t)a * 96 + 32 + q * 4];
            float4 z4 = *(const float4*)&v_acc[(size_t)a * 96 + 64 + q * 4];
            {
                int j = q * 4 + 0;
                *(float4*)&g_all[(size_t)a * 128 + j * 4] =
                    make_float4(gs[j], sc[j] * x4.x, sc[j] * y4.x, sc[j] * z4.x);
            }
            {
                int j = q * 4 + 1;
                *(float4*)&g_all[(size_t)a * 128 + j * 4] =
                    make_float4(gs[j], sc[j] * x4.y, sc[j] * y4.y, sc[j] * z4.y);
            }
            {
                int j = q * 4 + 2;
                *(float4*)&g_all[(size_t)a * 128 + j * 4] =
                    make_float4(gs[j], sc[j] * x4.z, sc[j] * y4.z, sc[j] * z4.z);
            }
            {
                int j = q * 4 + 3;
                *(float4*)&g_all[(size_t)a * 128 + j * 4] =
                    make_float4(gs[j], sc[j] * x4.w, sc[j] * y4.w, sc[j] * z4.w);
            }
        }
    }
}

// ---------------- edge backward (tabulated): geometry + table lerp + fold; epilogue ------
// Planes sDq/sDt[f(32)][edge(32)] uint, pad 33: (q0,q1)/(t0,t1) f16 pairs. No MFMA.
__global__ __launch_bounds__(256) void edge_bwd_tab(
    const float* __restrict__ pos, const int* __restrict__ types,
    const int2* __restrict__ order_sd, const float* __restrict__ rtab,
    const float* __restrict__ temb, const float* __restrict__ g_all,
    float* __restrict__ forces, float4* __restrict__ fbuf, int E)
{
    __shared__ unsigned int sDq[4][32 * 33];
    __shared__ unsigned int sDt[4][32 * 33];
    __shared__ int sTy[4][32];
    __shared__ int sIx[4][32];
    __shared__ float sFr[4][32];
    __shared__ float sTemb[96];

    const int lane = threadIdx.x & 63;
    const int el = lane & 31;            // edge within wave
    const int fg = lane >> 5;            // f-group 0/1
    const int w = threadIdx.x >> 6;
    const int gbase = blockIdx.x * 128 + w * 32;

    for (int i = threadIdx.x; i < 96; i += 256) sTemb[i] = temb[i];
    __syncthreads();

    // ---- phase 0: edge descriptors; geometry on lanes 0..31 ----
    const int p_e = gbase + el;
    const bool valid = (p_e < E);
    int2 sd = valid ? order_sd[p_e] : make_int2(0, 0);
    const int dstI = sd.y;
    const int key = valid ? sd.y : (-2 - el);

    float rinv = 1.f, env = 0.f, denv = 0.f, rhx = 0.f, rhy = 0.f, rhz = 0.f;
    if (lane < 32) {
        float rx = (pos[sd.y * 3 + 0] - pos[sd.x * 3 + 0]) * NM2A_C;
        float ry = (pos[sd.y * 3 + 1] - pos[sd.x * 3 + 1]) * NM2A_C;
        float rz = (pos[sd.y * 3 + 2] - pos[sd.x * 3 + 2]) * NM2A_C;
        float r2 = rx * rx + ry * ry + rz * rz + 1e-12f;
        float r = sqrtf(r2);
        rinv = 1.0f / r;
        float x = r * (1.0f / RCUT_C);
        float x2 = x * x, x4 = x2 * x2, x5 = x4 * x, x6 = x4 * x2, x7 = x6 * x, x8 = x6 * x2;
        env = (x < 1.0f) ? (1.0f - 28.0f * x6 + 48.0f * x7 - 21.0f * x8) : 0.0f;
        denv = (x < 1.0f) ? (-168.0f * x5 + 336.0f * x6 - 168.0f * x7) * (1.0f / RCUT_C) : 0.0f;
        rhx = rx * rinv; rhy = ry * rinv; rhz = rz * rinv;
        float xs = x * (float)(TBL - 1);
        int ti = min((int)xs, TBL - 2);
        sIx[w][el] = ti;
        sFr[w][el] = xs - (float)ti;
        sTy[w][el] = types[sd.x];
    }

    // ---- g_all prefetch for this lane's f-group (hidden under stage B) ----
    const float* gb = g_all + (size_t)dstI * 128;
    float4 gg[8];
    #pragma unroll
    for (int i = 0; i < 8; i++) gg[i] = *(const float4*)(gb + (fg * 16 + i) * 4);

    // ---- stage B: 2 lanes/edge; h=0 lerps q[64], h=1 lerps t[64]; pack (c,c+32) ----
    {
        const int m = lane >> 1, h = lane & 1;
        const int ti = sIx[w][m];
        const float fr = sFr[w][m];
        const int ty = sTy[w][m];
        const float* r0 = rtab + (size_t)ti * 128 + h * 64;
        const float* r1 = r0 + 128;
        unsigned int* plane = h ? &sDt[w][0] : &sDq[w][0];
        #pragma unroll
        for (int c4 = 0; c4 < 8; c4++) {
            f32x4 alo = *(const f32x4*)(r0 + c4 * 4);
            f32x4 blo = *(const f32x4*)(r1 + c4 * 4);
            f32x4 ahi = *(const f32x4*)(r0 + 32 + c4 * 4);
            f32x4 bhi = *(const f32x4*)(r1 + 32 + c4 * 4);
            #pragma unroll
            for (int j = 0; j < 4; j++) {
                int c = c4 * 4 + j;
                float hs = sTemb[ty * 32 + c];
                float lo = (alo[j] + fr * (blo[j] - alo[j])) * hs;
                float hi = (ahi[j] + fr * (bhi[j] - ahi[j])) * hs;
                plane[c * 33 + m] = pk2_(lo, hi);
            }
        }
    }

    // ---- epilogue: 2 lanes per edge (f split in 2), 1-step reduce ----
    {
        float Aa = 0.f, Bb = 0.f, Cc = 0.f, Pp = 0.f;
        float Ap = 0.f, Bp = 0.f, Cp = 0.f, Qq = 0.f;
        #pragma unroll
        for (int ff = 0; ff < 16; ff++) {
            const int f = fg * 16 + ff;
            unsigned int qx = sDq[w][f * 33 + el];
            unsigned int qy = sDt[w][f * 33 + el];
            float rw0 = lo16_(qx), rw1 = hi16_(qx);
            float u0 = lo16_(qy), u1 = hi16_(qy);
            float4 g4 = (ff < 8) ? gg[ff] : *(const float4*)(gb + f * 4);
            Pp += rw0 * g4.x; Qq += u0 * g4.x;
            Aa += rw1 * g4.y; Bb += rw1 * g4.z; Cc += rw1 * g4.w;
            Ap += u1 * g4.y;  Bp += u1 * g4.z;  Cp += u1 * g4.w;
        }
        Pp += __shfl_xor(Pp, 32, 64); Qq += __shfl_xor(Qq, 32, 64);
        Aa += __shfl_xor(Aa, 32, 64); Bb += __shfl_xor(Bb, 32, 64);
        Cc += __shfl_xor(Cc, 32, 64); Ap += __shfl_xor(Ap, 32, 64);
        Bp += __shfl_xor(Bp, 32, 64); Cp += __shfl_xor(Cp, 32, 64);

        if (lane < 32) {
            float Gx = env * Aa, Gy = env * Bb, Gz = env * Cc;
            float genv = Pp + rhx * Aa + rhy * Bb + rhz * Cc;
            float pc = env * (Qq + rhx * Ap + rhy * Bp + rhz * Cp) + genv * denv;
            float dotg = Gx * rhx + Gy * rhy + Gz * rhz;
            float cx = pc * rhx + (Gx - dotg * rhx) * rinv;
            float cy = pc * rhy + (Gy - dotg * rhy) * rinv;
            float cz = pc * rhz + (Gz - dotg * rhz) * rinv;

            const float SC = EV2KJ_C * NM2A_C;
            if (valid) fbuf[p_e] = make_float4(SC * cx, SC * cy, SC * cz, 0.0f);

            int kk = key;
            #pragma unroll
            for (int d = 1; d < 32; d <<= 1) {
                float ux = __shfl_up(cx, d, 32);
                float uy = __shfl_up(cy, d, 32);
                float uz = __shfl_up(cz, d, 32);
                int uk = __shfl_up(kk, d, 32);
                if (el >= d && uk == kk) { cx += ux; cy += uy; cz += uz; }
            }
            int nk = __shfl_down(kk, 1, 32);
            bool leader = (el == 31) || (nk != kk);
            if (valid && leader) {
                unsafeAtomicAdd(&forces[(size_t)dstI * 3 + 0], -SC * cx);
                unsafeAtomicAdd(&forces[(size_t)dstI * 3 + 1], -SC * cy);
                unsafeAtomicAdd(&forces[(size_t)dstI * 3 + 2], -SC * cz);
            }
        }
    }
}

// ------- src gather via src-bins: LDS per-atom accumulation, few contiguous atomics -------
__global__ __launch_bounds__(256) void gather_src(
    float* __restrict__ forces, const int* __restrict__ sbbase,
    const int2* __restrict__ srcbin, const float4* __restrict__ fbuf,
    int ssh, int N)
{
    __shared__ float acc[3072];   // 1024 atoms x 3
    const int wg = blockIdx.x;
    const int b = wg / GSPLIT, part = wg % GSPLIT;
    const int base = sbbase[b];
    const int cnt = sbbase[b + 1] - base;
    const int r0 = base + (int)((long long)cnt * part / GSPLIT);
    const int r1 = base + (int)((long long)cnt * (part + 1) / GSPLIT);
    const int abase = b << ssh;
    const bool lok = (ssh <= 10);
    for (int i = threadIdx.x; i < 3072; i += 256) acc[i] = 0.f;
    __syncthreads();
    for (int i = r0 + threadIdx.x; i < r1; i += 256) {
        int2 r = srcbin[i];
        float4 f = fbuf[r.y];
        if (lok) {
            int la = r.x - abase;
            atomicAdd(&acc[la * 3 + 0], f.x);
            atomicAdd(&acc[la * 3 + 1], f.y);
            atomicAdd(&acc[la * 3 + 2], f.z);
        } else {
            unsafeAtomicAdd(&forces[(size_t)r.x * 3 + 0], f.x);
            unsafeAtomicAdd(&forces[(size_t)r.x * 3 + 1], f.y);
            unsafeAtomicAdd(&forces[(size_t)r.x * 3 + 2], f.z);
        }
    }
    __syncthreads();
    if (lok) {
        for (int la = threadIdx.x; la < 1024; la += 256) {
            int a = abase + la;
            if (a < N) {
                float ax = acc[la * 3 + 0], ay = acc[la * 3 + 1], az = acc[la * 3 + 2];
                if (ax != 0.f || ay != 0.f || az != 0.f) {
                    unsafeAtomicAdd(&forces[(size_t)a * 3 + 0], ax);
                    unsafeAtomicAdd(&forces[(size_t)a * 3 + 1], ay);
                    unsafeAtomicAdd(&forces[(size_t)a * 3 + 2], az);
                }
            }
        }
    }
}

// ---------------- reductions & correction ----------------
__global__ __launch_bounds__(256) void reduce_net(
    const float* __restrict__ f, const float* __restrict__ masses,
    float* __restrict__ accum, int N)
{
    float nx = 0, ny = 0, nz = 0, ms = 0;
    for (int i = blockIdx.x * 256 + threadIdx.x; i < N; i += gridDim.x * 256) {
        nx += f[i * 3 + 0]; ny += f[i * 3 + 1]; nz += f[i * 3 + 2]; ms += masses[i];
    }
    #pragma unroll
    for (int m = 32; m; m >>= 1) {
        nx += __shfl_xor(nx, m, 64);
        ny += __shfl_xor(ny, m, 64);
        nz += __shfl_xor(nz, m, 64);
        ms += __shfl_xor(ms, m, 64);
    }
    __shared__ float red[4][4];
    int w = threadIdx.x >> 6;
    if ((threadIdx.x & 63) == 0) { red[w][0] = nx; red[w][1] = ny; red[w][2] = nz; red[w][3] = ms; }
    __syncthreads();
    if (threadIdx.x == 0) {
        float a0 = 0, a1 = 0, a2 = 0, a3 = 0;
        for (int i = 0; i < 4; i++) { a0 += red[i][0]; a1 += red[i][1]; a2 += red[i][2]; a3 += red[i][3]; }
        unsafeAtomicAdd(accum + 0, a0);
        unsafeAtomicAdd(accum + 1, a1);
        unsafeAtomicAdd(accum + 2, a2);
        unsafeAtomicAdd(accum + 3, a3);
    }
}

__global__ __launch_bounds__(256) void correct_forces(
    float* __restrict__ f, const float* __restrict__ masses,
    const float* __restrict__ accum, int N)
{
    int i = blockIdx.x * 256 + threadIdx.x;
    if (i < N) {
        float c = masses[i] / accum[3];
        f[i * 3 + 0] -= c * accum[0];
        f[i * 3 + 1] -= c * accum[1];
        f[i * 3 + 2] -= c * accum[2];
    }
}

extern "C" void kernel_launch(void* const* d_in, const int* in_sizes, int n_in,
                              void* d_out, int out_size, void* d_ws, size_t ws_size,
                              hipStream_t stream)
{
    (void)n_in; (void)ws_size;
    const float* pos    = (const float*)d_in[0];
    const float* masses = (const float*)d_in[1];
    const float* temb   = (const float*)d_in[2];
    const float* Wr1    = (const float*)d_in[3];
    const float* br1    = (const float*)d_in[4];
    const float* Wr2    = (const float*)d_in[5];
    const float* Wself  = (const float*)d_in[6];
    const float* Wo1    = (const float*)d_in[7];
    const float* bo1    = (const float*)d_in[8];
    const float* Wo2    = (const float*)d_in[9];
    const int* types    = (const int*)d_in[10];
    const int* eidx     = (const int*)d_in[11];
    const int N = in_sizes[1];
    const int E = in_sizes[11] / 2;

    float* out = (float*)d_out;
    float* forces = out + 1;

    // bucket geometry (dst buckets <=512, src buckets <=64)
    int dsh = 7;  while (((N + (1 << dsh) - 1) >> dsh) > 512) dsh++;
    int nbd = (N + (1 << dsh) - 1) >> dsh;
    int ssh = 10; while (((N + (1 << ssh) - 1) >> ssh) > 64) ssh++;
    int nbs = (N + (1 << ssh) - 1) >> ssh;

    float* ws = (float*)d_ws;
    float* s_acc = ws;                               // N*32
    float* v_acc = s_acc + (size_t)N * FDIM;         // N*96
    float* g_all = v_acc + (size_t)N * 96;           // N*128
    float* accum = g_all + (size_t)N * 128;          // 4
    int* meta = (int*)(accum + 4);
    int* dbcnt  = meta;                              // 512
    int* sbcnt  = dbcnt + 512;                       // 64
    int* dbcur  = sbcnt + 64;                        // 512
    int* sbcur  = dbcur + 512;                       // 64
    int* dbbase = sbcur + 64;                        // 513
    int* sbbase = dbbase + 513;                      // 65
    int2* order_sd = (int2*)(((uintptr_t)(sbbase + 65) + 15) & ~(uintptr_t)15);  // E
    int2* srcbin   = order_sd + E;                                               // E
    float4* fbuf   = (float4*)(((uintptr_t)(srcbin + E) + 15) & ~(uintptr_t)15); // E
    float* rtab    = (float*)(fbuf + E);                                         // TBL*128 (1 MB)

    hipMemsetAsync(d_out, 0, (size_t)out_size * sizeof(float), stream);
    hipMemsetAsync(s_acc, 0, (size_t)N * 128 * sizeof(float), stream);
    hipMemsetAsync(meta, 0, 1152 * sizeof(int), stream);   // dbcnt|sbcnt|dbcur|sbcur
    hipMemsetAsync(accum, 0, 4 * sizeof(float), stream);

    build_rtab<<<TBL, 64, 0, stream>>>(Wr1, br1, Wr2, rtab);
    hist_buckets<<<512, 256, 0, stream>>>(eidx, dbcnt, sbcnt, E, dsh, ssh, nbd, nbs);
    scan_bases<<<1, 512, 0, stream>>>(dbcnt, sbcnt, dbbase, sbbase, nbd, nbs);
    int nBin = (E + BINW - 1) / BINW;
    bin_dst<<<nBin, 256, 0, stream>>>(eidx, dbbase, dbcur, order_sd, E, dsh, nbd);
    sort_bucket<<<nbd, 256, 0, stream>>>(order_sd, dbbase, sbcur, sbbase, srcbin, dsh, ssh);

    int nAtomBlocks = (N + 63) / 64;
    int nFwdBlocks = (E + 127) / 128;
    int nBwdBlocks = (E + 127) / 128;
    edge_fwd_tab<<<nFwdBlocks, 256, 0, stream>>>(pos, types, order_sd, rtab, temb,
                                                 s_acc, v_acc, E);
    atom_mlp<<<nAtomBlocks, 64, 0, stream>>>(types, temb, Wself, Wo1, bo1, Wo2,
                                             s_acc, v_acc, g_all, out, N);
    edge_bwd_tab<<<nBwdBlocks, 256, 0, stream>>>(pos, types, order_sd, rtab, temb,
                                                 g_all, forces, fbuf, E);
    gather_src<<<nbs * GSPLIT, 256, 0, stream>>>(forces, sbbase, srcbin, fbuf, ssh, N);
    reduce_net<<<64, 256, 0, stream>>>(forces, masses, accum, N);
    correct_forces<<<(N + 255) / 256, 256, 0, stream>>>(forces, masses, accum, N);
}

// Round 11
// 366.043 us; speedup vs baseline: 1.3614x; 1.3614x over previous
//
#include <hip/hip_runtime.h>
#include <math.h>

#define FDIM 32
#define NBASIS 8
#define QP 40     // A-stage row pad (f16 units) -> 80B rows, 16B-aligned quads
#define DS2 34    // bwd D-stage stride (uint2 units); 16B-aligned uint4 stores, ~2-way banks
#define BINW 4096 // edges per bin_dst window
#define DCAP 4096 // sort_bucket LDS record capacity
#define GSPLIT 8  // gather WGs per src bucket

constexpr float RCUT_C = 20.0f;
constexpr float PI_F = 3.14159265358979323846f;
constexpr float EV2KJ_C = 96.4853f;
constexpr float NM2A_C = 10.0f;

typedef _Float16 f16x8 __attribute__((ext_vector_type(8)));
typedef _Float16 f16x4 __attribute__((ext_vector_type(4)));
typedef float f32x4 __attribute__((ext_vector_type(4)));

__device__ __forceinline__ float sigmoidf_(float z) { return 1.0f / (1.0f + __expf(-z)); }

__device__ __forceinline__ unsigned int pk2_(float a, float b) {
    unsigned short lo = __builtin_bit_cast(unsigned short, (_Float16)a);
    unsigned short hi = __builtin_bit_cast(unsigned short, (_Float16)b);
    return (unsigned int)lo | ((unsigned int)hi << 16);
}
__device__ __forceinline__ float lo16_(unsigned int v) {
    return (float)__builtin_bit_cast(_Float16, (unsigned short)(v & 0xffffu));
}
__device__ __forceinline__ float hi16_(unsigned int v) {
    return (float)__builtin_bit_cast(_Float16, (unsigned short)(v >> 16));
}

// ---------------- bucketed CSR build (no N-wide scans, no random scatter) ----------------
__global__ __launch_bounds__(256) void hist_buckets(
    const int* __restrict__ eidx, int* __restrict__ dbcnt, int* __restrict__ sbcnt,
    int E, int dsh, int ssh, int nbd, int nbs)
{
    __shared__ int ld[512];
    __shared__ int ls[64];
    for (int i = threadIdx.x; i < nbd; i += 256) ld[i] = 0;
    for (int i = threadIdx.x; i < nbs; i += 256) ls[i] = 0;
    __syncthreads();
    for (int e = blockIdx.x * 256 + threadIdx.x; e < E; e += gridDim.x * 256) {
        int s = eidx[e];
        int d = eidx[E + e];
        atomicAdd(&ld[d >> dsh], 1);
        atomicAdd(&ls[s >> ssh], 1);
    }
    __syncthreads();
    for (int i = threadIdx.x; i < nbd; i += 256) if (ld[i]) atomicAdd(&dbcnt[i], ld[i]);
    for (int i = threadIdx.x; i < nbs; i += 256) if (ls[i]) atomicAdd(&sbcnt[i], ls[i]);
}

__global__ __launch_bounds__(512) void scan_bases(
    const int* __restrict__ dbcnt, const int* __restrict__ sbcnt,
    int* __restrict__ dbbase, int* __restrict__ sbbase, int nbd, int nbs)
{
    __shared__ int buf[512];
    const int t = threadIdx.x;
    int v = (t < nbd) ? dbcnt[t] : 0;
    buf[t] = v;
    __syncthreads();
    for (int off = 1; off < 512; off <<= 1) {
        int u = (t >= off) ? buf[t - off] : 0;
        __syncthreads();
        buf[t] += u;
        __syncthreads();
    }
    if (t < nbd) dbbase[t] = buf[t] - v;
    if (t == 511) dbbase[nbd] = buf[511];
    __syncthreads();
    int v2 = (t < nbs) ? sbcnt[t] : 0;
    buf[t] = v2;
    __syncthreads();
    for (int off = 1; off < 512; off <<= 1) {
        int u = (t >= off) ? buf[t - off] : 0;
        __syncthreads();
        buf[t] += u;
        __syncthreads();
    }
    if (t < nbs) sbbase[t] = buf[t] - v2;
    if (t == 511) sbbase[nbs] = buf[511];
}

__global__ __launch_bounds__(256) void bin_dst(
    const int* __restrict__ eidx, const int* __restrict__ dbbase,
    int* __restrict__ dbcur, int2* __restrict__ order_sd,
    int E, int dsh, int nbd)
{
    __shared__ int2 rec[BINW];          // 32 KB
    __shared__ int lcnt[512], lbase[512], lofs[512];
    const int t = threadIdx.x;
    const int w0 = blockIdx.x * BINW;
    const int n = min(BINW, E - w0);
    if (n <= 0) return;
    for (int i = t; i < nbd; i += 256) lcnt[i] = 0;
    __syncthreads();
    for (int i = t; i < n; i += 256) {
        int e = w0 + i;
        int2 r = make_int2(eidx[e], eidx[E + e]);
        rec[i] = r;
        atomicAdd(&lcnt[r.y >> dsh], 1);
    }
    __syncthreads();
    for (int i = t; i < nbd; i += 256) {
        int c = lcnt[i];
        lbase[i] = c ? atomicAdd(&dbcur[i], c) : 0;
        lofs[i] = 0;
    }
    __syncthreads();
    for (int i = t; i < n; i += 256) {
        int2 r = rec[i];
        int b = r.y >> dsh;
        int pos = lbase[b] + atomicAdd(&lofs[b], 1);
        order_sd[dbbase[b] + pos] = r;
    }
}

__global__ __launch_bounds__(256) void sort_bucket(
    int2* __restrict__ order_sd, const int* __restrict__ dbbase,
    int* __restrict__ sbcur, const int* __restrict__ sbbase,
    int2* __restrict__ srcbin, int dsh, int ssh)
{
    __shared__ int2 rec[DCAP];          // 32 KB
    __shared__ int c128[128], o128[128];
    __shared__ int sc[64], sbres[64], so[64];
    const int b = blockIdx.x, t = threadIdx.x;
    const int base = dbbase[b];
    const int cnt = dbbase[b + 1] - base;
    const bool dosort = (dsh <= 7);
    const int kmask = (1 << dsh) - 1;

    for (int start = 0; start < cnt; start += DCAP) {
        const int n = min(DCAP, cnt - start);
        if (t < 128) c128[t] = 0;
        if (t < 64) sc[t] = 0;
        __syncthreads();
        for (int i = t; i < n; i += 256) {
            int2 r = order_sd[base + start + i];
            rec[i] = r;
            if (dosort) atomicAdd(&c128[r.y & kmask], 1);
            atomicAdd(&sc[r.x >> ssh], 1);
        }
        __syncthreads();
        int v0 = (t < 128) ? c128[t] : 0;
        __syncthreads();
        for (int off = 1; off < 128; off <<= 1) {
            int u = (t < 128 && t >= off) ? c128[t - off] : 0;
            __syncthreads();
            if (t < 128) c128[t] += u;
            __syncthreads();
        }
        if (t < 128) o128[t] = c128[t] - v0;
        if (t < 64) {
            int c = sc[t];
            sbres[t] = c ? atomicAdd(&sbcur[t], c) : 0;
            so[t] = 0;
        }
        __syncthreads();
        for (int i = t; i < n; i += 256) {
            int2 r = rec[i];
            int p;
            if (dosort) {
                int pos = atomicAdd(&o128[r.y & kmask], 1);
                p = base + start + pos;
                order_sd[p] = r;
            } else {
                p = base + start + i;
            }
            int sb2 = r.x >> ssh;
            int slot = sbres[sb2] + atomicAdd(&so[sb2], 1);
            srcbin[sbbase[sb2] + slot] = make_int2(r.x, p);
        }
        __syncthreads();
    }
}

// ---------------- weight fragment pre-pack: per-lane MFMA B operands ----------------
__global__ __launch_bounds__(64) void pack_wfrag(
    const float* __restrict__ Wr1, const float* __restrict__ Wr2,
    _Float16* __restrict__ wpack)
{
    const int lane = threadIdx.x;          // 0..63
    const int kb = (lane >> 4) * 8, nb = lane & 15;
    _Float16* o = wpack + (size_t)lane * 64;
    #pragma unroll
    for (int t = 0; t < 2; t++)
        #pragma unroll
        for (int j = 0; j < 8; j++) {
            int k = kb + j;
            o[t * 8 + j] = (k < 8) ? (_Float16)Wr1[k * FDIM + t * 16 + nb] : (_Float16)0.0f;
        }
    #pragma unroll
    for (int t = 0; t < 4; t++)
        #pragma unroll
        for (int j = 0; j < 8; j++)
            o[16 + t * 8 + j] = (_Float16)Wr2[(kb + j) * 64 + t * 16 + nb];
    #pragma unroll
    for (int t = 0; t < 2; t++)
        #pragma unroll
        for (int j = 0; j < 8; j++) {
            int k = kb + j;
            o[48 + t * 8 + j] = (k >= 8 && k < 16) ? (_Float16)Wr1[(k - 8) * FDIM + t * 16 + nb]
                                                   : (_Float16)0.0f;
        }
}

// ---------------- edge forward: hs*env folded into packed D; LDS-stashed keys ----------------
// Phase-3: ONE wave run-merges all 32 contiguous edges; 128 output channels spread
// across 64 lanes (lane<32: s[ch]+vy[ch]; lane>=32: vx[ch]+vz[ch]); 2 atomics per flush.
__global__ __launch_bounds__(256) void edge_fwd_mfma(
    const float* __restrict__ pos, const int* __restrict__ types,
    const int2* __restrict__ order_sd,
    const _Float16* __restrict__ wpack, const float* __restrict__ br1,
    const float* __restrict__ temb,
    float* __restrict__ s_acc, float* __restrict__ v_acc, int E)
{
    __shared__ __align__(16) _Float16 sR[4][2560];
    __shared__ float sSt[4][32][4];         // env, rhx, rhy, rhz
    __shared__ int sTy[4][32];
    __shared__ int sKey[4][32];
    __shared__ float sTemb[96];

    const int lane = threadIdx.x & 63;
    const int l32 = threadIdx.x & 31;
    const int w = threadIdx.x >> 6;
    const int gbase = blockIdx.x * 128 + w * 32;

    for (int i = threadIdx.x; i < 96; i += 256) sTemb[i] = temb[i];
    __syncthreads();

    const int kb = (lane >> 4) * 8;
    const f16x8* wp = (const f16x8*)(wpack + (size_t)lane * 64);
    f16x8 bz[2] = { wp[0], wp[1] };
    f16x8 bf[4] = { wp[2], wp[3], wp[4], wp[5] };

    // ---- phase 0: lane-parallel geometry + basis (lanes 0..31) ----
    if (lane < 32) {
        const int ed = l32;
        const int p = gbase + ed;
        const bool vld = (p < E);
        int2 sd = vld ? order_sd[p] : make_int2(0, 0);
        float rx = (pos[sd.y * 3 + 0] - pos[sd.x * 3 + 0]) * NM2A_C;
        float ry = (pos[sd.y * 3 + 1] - pos[sd.x * 3 + 1]) * NM2A_C;
        float rz = (pos[sd.y * 3 + 2] - pos[sd.x * 3 + 2]) * NM2A_C;
        float r2 = rx * rx + ry * ry + rz * rz + 1e-12f;
        float r = sqrtf(r2);
        float rinv = 1.0f / r;
        float x = r * (1.0f / RCUT_C);
        float x2 = x * x, x4 = x2 * x2, x6 = x4 * x2, x7 = x6 * x, x8 = x6 * x2;
        float env = (x < 1.0f) ? (1.0f - 28.0f * x6 + 48.0f * x7 - 21.0f * x8) : 0.0f;

        float th = PI_F * x, s1, c1;
        __sincosf(th, &s1, &c1);
        float sp = 0.0f, sn = s1;
        _Float16 av[8];
        #pragma unroll
        for (int n = 0; n < NBASIS; n++) {
            av[n] = (_Float16)(sn * rinv);
            float snx = 2.0f * c1 * sn - sp; sp = sn; sn = snx;
        }
        _Float16* dstA = &sR[w][(ed < 16 ? 0 : 640) + (ed & 15) * QP];
        *(f16x8*)&dstA[0] = *(f16x8*)&av[0];
        *(float4*)&dstA[8]  = make_float4(0.f, 0.f, 0.f, 0.f);
        *(float4*)&dstA[16] = make_float4(0.f, 0.f, 0.f, 0.f);
        *(float4*)&dstA[24] = make_float4(0.f, 0.f, 0.f, 0.f);
        sSt[w][ed][0] = env;
        sSt[w][ed][1] = rx * rinv;
        sSt[w][ed][2] = ry * rinv;
        sSt[w][ed][3] = rz * rinv;
        sTy[w][ed] = types[sd.x];
        sKey[w][ed] = vld ? sd.y : -1;
    }

    // ---- phase 1: MFMA basis layer -> z, silu -> Q (both tiles) ----
    {
        const int me = lane & 15;
        f16x8 a1a = *(const f16x8*)&sR[w][me * QP + kb];
        f16x8 a1b = *(const f16x8*)&sR[w][640 + me * QP + kb];
        const f32x4 z4 = {0.f, 0.f, 0.f, 0.f};
        f32x4 Dz0a = __builtin_amdgcn_mfma_f32_16x16x32_f16(a1a, bz[0], z4, 0, 0, 0);
        f32x4 Dz1a = __builtin_amdgcn_mfma_f32_16x16x32_f16(a1a, bz[1], z4, 0, 0, 0);
        f32x4 Dz0b = __builtin_amdgcn_mfma_f32_16x16x32_f16(a1b, bz[0], z4, 0, 0, 0);
        f32x4 Dz1b = __builtin_amdgcn_mfma_f32_16x16x32_f16(a1b, bz[1], z4, 0, 0, 0);
        const int f0 = lane & 15, e0 = (lane >> 4) * 4;
        const float bb0 = br1[f0], bb1 = br1[16 + f0];
        #pragma unroll
        for (int t = 0; t < 2; t++) {
            f32x4 Dza = t ? Dz1a : Dz0a;
            f32x4 Dzb = t ? Dz1b : Dz0b;
            float bb = t ? bb1 : bb0;
            #pragma unroll
            for (int r = 0; r < 4; r++) {
                float za = Dza[r] + bb;
                float zb = Dzb[r] + bb;
                sR[w][1280 + (e0 + r) * QP + t * 16 + f0] = (_Float16)(za * sigmoidf_(za));
                sR[w][1920 + (e0 + r) * QP + t * 16 + f0] = (_Float16)(zb * sigmoidf_(zb));
            }
        }
    }

    // ---- phase 2: MFMA W2; fold hs*env; pack (ch, ch+32) pairs; D[edge*32+ch] ----
    {
        const int me = lane & 15;
        f16x8 aqa = *(const f16x8*)&sR[w][1280 + me * QP + kb];
        f16x8 aqb = *(const f16x8*)&sR[w][1920 + me * QP + kb];
        const int cb = lane & 15, e0 = (lane >> 4) * 4;
        float hev[2][2][4];   // [tile][fpair][r] = hs(ch)*env
        #pragma unroll
        for (int tl = 0; tl < 2; tl++)
            #pragma unroll
            for (int fp = 0; fp < 2; fp++)
                #pragma unroll
                for (int r = 0; r < 4; r++) {
                    int ed = tl * 16 + e0 + r;
                    hev[tl][fp][r] = sTemb[sTy[w][ed] * 32 + fp * 16 + cb] * sSt[w][ed][0];
                }
        const f32x4 z4 = {0.f, 0.f, 0.f, 0.f};
        unsigned int* DU = (unsigned int*)&sR[w][0];
        #pragma unroll
        for (int fp = 0; fp < 2; fp++) {
            f32x4 a0 = __builtin_amdgcn_mfma_f32_16x16x32_f16(aqa, bf[fp],     z4, 0, 0, 0);
            f32x4 a1 = __builtin_amdgcn_mfma_f32_16x16x32_f16(aqa, bf[fp + 2], z4, 0, 0, 0);
            f32x4 b0 = __builtin_amdgcn_mfma_f32_16x16x32_f16(aqb, bf[fp],     z4, 0, 0, 0);
            f32x4 b1 = __builtin_amdgcn_mfma_f32_16x16x32_f16(aqb, bf[fp + 2], z4, 0, 0, 0);
            #pragma unroll
            for (int r = 0; r < 4; r++) {
                float ha = hev[0][fp][r], hb = hev[1][fp][r];
                DU[(e0 + r) * 32 + fp * 16 + cb]        = pk2_(a0[r] * ha, a1[r] * ha);
                DU[(16 + e0 + r) * 32 + fp * 16 + cb]   = pk2_(b0[r] * hb, b1[r] * hb);
            }
        }
    }

    // ---- phase 3: full-wave contiguous run-merge over 32 edges; 2 atomics/flush ----
    {
        const unsigned int* DU = (const unsigned int*)&sR[w][0];
        const bool loHalf = (lane < 32);
        const int mmax = min(32, E - gbase);
        int runKey = -1;
        float a0 = 0.f, a1 = 0.f;
        for (int m = 0; m < mmax; m++) {
            int k = sKey[w][m];
            if (k != runKey) {
                if (runKey >= 0) {
                    float* p0 = loHalf ? &s_acc[(size_t)runKey * 32 + l32]
                                       : &v_acc[(size_t)runKey * 96 + l32];
                    float* p1 = loHalf ? &v_acc[(size_t)runKey * 96 + 32 + l32]
                                       : &v_acc[(size_t)runKey * 96 + 64 + l32];
                    unsafeAtomicAdd(p0, a0);
                    unsafeAtomicAdd(p1, a1);
                }
                runKey = k;
                a0 = a1 = 0.f;
            }
            unsigned int qp = DU[m * 32 + l32];
            float lo = lo16_(qp), hi = hi16_(qp);
            float rA = sSt[w][m][1], rY = sSt[w][m][2], rZ = sSt[w][m][3];
            a0 += loHalf ? lo : hi * rA;
            a1 += hi * (loHalf ? rY : rZ);
        }
        if (runKey >= 0) {
            float* p0 = loHalf ? &s_acc[(size_t)runKey * 32 + l32]
                               : &v_acc[(size_t)runKey * 96 + l32];
            float* p1 = loHalf ? &v_acc[(size_t)runKey * 96 + 32 + l32]
                               : &v_acc[(size_t)runKey * 96 + 64 + l32];
            unsafeAtomicAdd(p0, a0);
            unsafeAtomicAdd(p1, a1);
        }
    }
}

// -------- atom MLP v3: one atom per thread, phased register lifetimes (no spill) ----
__global__ __launch_bounds__(64) void atom_mlp(
    const int* __restrict__ types, const float* __restrict__ temb,
    const float* __restrict__ Wself, const float* __restrict__ Wo1,
    const float* __restrict__ bo1, const float* __restrict__ Wo2,
    const float* __restrict__ s_acc, const float* __restrict__ v_acc,
    float* __restrict__ g_all, float* __restrict__ out, int N)
{
    __shared__ __align__(16) float sWs[FDIM * FDIM];        // 32x32
    __shared__ __align__(16) float sWo1[2 * FDIM * FDIM];   // 64x32
    __shared__ __align__(16) float sb[FDIM], sW2o[FDIM], sTE[96];
    const int t = threadIdx.x;
    for (int i = t; i < FDIM * FDIM; i += 64) sWs[i] = Wself[i];
    for (int i = t; i < 2 * FDIM * FDIM; i += 64) sWo1[i] = Wo1[i];
    if (t < FDIM) { sb[t] = bo1[t]; sW2o[t] = Wo2[t]; }
    for (int i = t; i < 96; i += 64) sTE[i] = temb[i];
    __syncthreads();

    int a = blockIdx.x * 64 + t;
    const bool valid = (a < N);
    if (!valid) a = 0;
    const int ty = types[a];

    float u[32];                       // becomes gu in phase C
    {
        float row[32];
        #pragma unroll
        for (int j = 0; j < 32; j++) row[j] = sTE[ty * FDIM + j];
        {
            float s_[32];
            #pragma unroll
            for (int q = 0; q < 8; q++) {
                float4 v = *(const float4*)&s_acc[(size_t)a * FDIM + q * 4];
                s_[q * 4 + 0] = v.x; s_[q * 4 + 1] = v.y;
                s_[q * 4 + 2] = v.z; s_[q * 4 + 3] = v.w;
            }
            #pragma unroll
            for (int k = 0; k < 32; k++) {
                float sk = s_[k];
                #pragma unroll
                for (int q = 0; q < 8; q++) {
                    float4 wv = *(const float4*)&sWs[k * 32 + q * 4];
                    row[q * 4 + 0] += sk * wv.x; row[q * 4 + 1] += sk * wv.y;
                    row[q * 4 + 2] += sk * wv.z; row[q * 4 + 3] += sk * wv.w;
                }
            }
        }
        #pragma unroll
        for (int j = 0; j < 32; j++) u[j] = sb[j];
        #pragma unroll
        for (int k = 0; k < 32; k++) {
            float rk = row[k];
            #pragma unroll
            for (int q = 0; q < 8; q++) {
                float4 w1 = *(const float4*)&sWo1[k * 32 + q * 4];
                u[q * 4 + 0] += rk * w1.x; u[q * 4 + 1] += rk * w1.y;
                u[q * 4 + 2] += rk * w1.z; u[q * 4 + 3] += rk * w1.w;
            }
        }
    }

    float vn[32];
    #pragma unroll
    for (int q = 0; q < 8; q++) {
        float4 x4 = *(const float4*)&v_acc[(size_t)a * 96 +      q * 4];
        float4 y4 = *(const float4*)&v_acc[(size_t)a * 96 + 32 + q * 4];
        float4 z4 = *(const float4*)&v_acc[(size_t)a * 96 + 64 + q * 4];
        vn[q * 4 + 0] = sqrtf(x4.x * x4.x + y4.x * y4.x + z4.x * z4.x + 1e-12f);
        vn[q * 4 + 1] = sqrtf(x4.y * x4.y + y4.y * y4.y + z4.y * z4.y + 1e-12f);
        vn[q * 4 + 2] = sqrtf(x4.z * x4.z + y4.z * y4.z + z4.z * z4.z + 1e-12f);
        vn[q * 4 + 3] = sqrtf(x4.w * x4.w + y4.w * y4.w + z4.w * z4.w + 1e-12f);
    }
    #pragma unroll
    for (int k = 0; k < 32; k++) {
        float vk = vn[k];
        #pragma unroll
        for (int q = 0; q < 8; q++) {
            float4 w2 = *(const float4*)&sWo1[(k + 32) * 32 + q * 4];
            u[q * 4 + 0] += vk * w2.x; u[q * 4 + 1] += vk * w2.y;
            u[q * 4 + 2] += vk * w2.z; u[q * 4 + 3] += vk * w2.w;
        }
    }

    {
        float pa = 0.0f;
        #pragma unroll
        for (int j = 0; j < 32; j++) {
            float z = u[j];
            float sg = sigmoidf_(z);
            pa += z * sg * sW2o[j];
            u[j] = sW2o[j] * (sg * (1.0f + z * (1.0f - sg)));   // gu
        }
        if (!valid) pa = 0.0f;
        #pragma unroll
        for (int m = 32; m; m >>= 1) pa += __shfl_xor(pa, m, 64);
        if (t == 0) unsafeAtomicAdd(out, pa * EV2KJ_C);
    }

    float sc[32];
    #pragma unroll
    for (int j = 0; j < 32; j++) {
        float av = 0.f;
        #pragma unroll
        for (int q = 0; q < 8; q++) {
            float4 w2 = *(const float4*)&sWo1[(j + 32) * 32 + q * 4];
            av += u[q * 4 + 0] * w2.x + u[q * 4 + 1] * w2.y
                + u[q * 4 + 2] * w2.z + u[q * 4 + 3] * w2.w;
        }
        sc[j] = av / vn[j];
    }

    float gfr[32];
    #pragma unroll
    for (int j = 0; j < 32; j++) {
        float ar = 0.f;
        #pragma unroll
        for (int q = 0; q < 8; q++) {
            float4 w1 = *(const float4*)&sWo1[j * 32 + q * 4];
            ar += u[q * 4 + 0] * w1.x + u[q * 4 + 1] * w1.y
                + u[q * 4 + 2] * w1.z + u[q * 4 + 3] * w1.w;
        }
        gfr[j] = ar;
    }

    float gs[32];
    #pragma unroll
    for (int j = 0; j < 32; j++) {
        float acc = 0.f;
        #pragma unroll
        for (int q = 0; q < 8; q++) {
            float4 wv = *(const float4*)&sWs[j * 32 + q * 4];
            acc += gfr[q * 4 + 0] * wv.x + gfr[q * 4 + 1] * wv.y
                 + gfr[q * 4 + 2] * wv.z + gfr[q * 4 + 3] * wv.w;
        }
        gs[j] = acc;
    }

    if (valid) {
        #pragma unroll
        for (int q = 0; q < 8; q++) {
            float4 x4 = *(const float4*)&v_acc[(size_t)a * 96 +      q * 4];
            float4 y4 = *(const float4*)&v_acc[(size_t)a * 96 + 32 + q * 4];
            float4 z4 = *(const float4*)&v_acc[(size_t)a * 96 + 64 + q * 4];
            {
                int j = q * 4 + 0;
                *(float4*)&g_all[(size_t)a * 128 + j * 4] =
                    make_float4(gs[j], sc[j] * x4.x, sc[j] * y4.x, sc[j] * z4.x);
            }
            {
                int j = q * 4 + 1;
                *(float4*)&g_all[(size_t)a * 128 + j * 4] =
                    make_float4(gs[j], sc[j] * x4.y, sc[j] * y4.y, sc[j] * z4.y);
            }
            {
                int j = q * 4 + 2;
                *(float4*)&g_all[(size_t)a * 128 + j * 4] =
                    make_float4(gs[j], sc[j] * x4.z, sc[j] * y4.z, sc[j] * z4.z);
            }
            {
                int j = q * 4 + 3;
                *(float4*)&g_all[(size_t)a * 128 + j * 4] =
                    make_float4(gs[j], sc[j] * x4.w, sc[j] * y4.w, sc[j] * z4.w);
            }
        }
    }
}

// ---------------- edge backward v3: 32 edges/wave; interleaved (q,t) D-stage; g prefetch ----
__global__ __launch_bounds__(256) void edge_bwd_mfma(
    const float* __restrict__ pos, const int* __restrict__ types,
    const int2* __restrict__ order_sd,
    const _Float16* __restrict__ wpack, const float* __restrict__ br1,
    const float* __restrict__ temb,
    const float* __restrict__ g_all,
    float* __restrict__ forces, float4* __restrict__ fbuf, int E)
{
    __shared__ __align__(16) _Float16 sW[4][4352];
    __shared__ int   sTy[4][32];
    __shared__ float sTemb[96];

    const int lane = threadIdx.x & 63;
    const int el = lane & 31;            // edge within wave
    const int w = threadIdx.x >> 6;
    const int gbase = blockIdx.x * 128 + w * 32;

    for (int i = threadIdx.x; i < 96; i += 256) sTemb[i] = temb[i];
    __syncthreads();

    const int kb = (lane >> 4) * 8;
    const f16x8* wp = (const f16x8*)(wpack + (size_t)lane * 64);
    f16x8 bz[2] = { wp[0], wp[1] };
    f16x8 bf[4] = { wp[2], wp[3], wp[4], wp[5] };
    f16x8 bt[2] = { wp[6], wp[7] };

    // ---- phase 0: edge descriptors; 2 lanes mirror each edge; geometry on lanes 0..31 ----
    const int p_e = gbase + el;
    const bool valid = (p_e < E);
    int2 sd = valid ? order_sd[p_e] : make_int2(0, 0);
    const int dstI = sd.y;
    const int key = valid ? sd.y : (-2 - el);

    float rinv = 1.f, env = 0.f, denv = 0.f, rhx = 0.f, rhy = 0.f, rhz = 0.f;
    if (lane < 32) {
        float rx = (pos[sd.y * 3 + 0] - pos[sd.x * 3 + 0]) * NM2A_C;
        float ry = (pos[sd.y * 3 + 1] - pos[sd.x * 3 + 1]) * NM2A_C;
        float rz = (pos[sd.y * 3 + 2] - pos[sd.x * 3 + 2]) * NM2A_C;
        float r2 = rx * rx + ry * ry + rz * rz + 1e-12f;
        float r = sqrtf(r2);
        rinv = 1.0f / r;
        float x = r * (1.0f / RCUT_C);
        float x2 = x * x, x4 = x2 * x2, x5 = x4 * x, x6 = x4 * x2, x7 = x6 * x, x8 = x6 * x2;
        env = (x < 1.0f) ? (1.0f - 28.0f * x6 + 48.0f * x7 - 21.0f * x8) : 0.0f;
        denv = (x < 1.0f) ? (-168.0f * x5 + 336.0f * x6 - 168.0f * x7) * (1.0f / RCUT_C) : 0.0f;
        rhx = rx * rinv; rhy = ry * rinv; rhz = rz * rinv;

        float th = PI_F * x, s1, c1;
        __sincosf(th, &s1, &c1);
        float sp = 0.0f, sn = s1, cp = 1.0f, cn = c1;
        _Float16 av[16];
        #pragma unroll
        for (int n = 0; n < NBASIS; n++) {
            float basis = sn * rinv;
            float dbdr = (PI_F * (float)(n + 1) * (1.0f / RCUT_C)) * cn * rinv - basis * rinv;
            av[n] = (_Float16)basis;
            av[8 + n] = (_Float16)dbdr;
            float snx = 2.0f * c1 * sn - sp; sp = sn; sn = snx;
            float cnx = 2.0f * c1 * cn - cp; cp = cn; cn = cnx;
        }
        _Float16* dstA = &sW[w][(el >> 4) * 640 + (el & 15) * QP];
        *(f16x8*)&dstA[0] = *(f16x8*)&av[0];
        *(f16x8*)&dstA[8] = *(f16x8*)&av[8];
        *(float4*)&dstA[16] = make_float4(0.f, 0.f, 0.f, 0.f);
        *(float4*)&dstA[24] = make_float4(0.f, 0.f, 0.f, 0.f);
        sTy[w][el] = types[sd.x];
    }

    // ---- g_all prefetch: first 8 of 16 rows for this lane's f-group ----
    const int fg = lane >> 5;
    const float* gb = g_all + (size_t)dstI * 128;
    float4 gg[8];
    #pragma unroll
    for (int i = 0; i < 8; i++) gg[i] = *(const float4*)(gb + (fg * 16 + i) * 4);

    // ---- phase 1: 8 MFMAs (z, tacc over 2 ch-tiles x 2 edge-tiles); silu/tf -> Q / T ----
    {
        const int me = lane & 15;
        f16x8 a1a = *(const f16x8*)&sW[w][me * QP + kb];
        f16x8 a1b = *(const f16x8*)&sW[w][640 + me * QP + kb];
        const f32x4 z4 = {0.f, 0.f, 0.f, 0.f};
        f32x4 Dz0a = __builtin_amdgcn_mfma_f32_16x16x32_f16(a1a, bz[0], z4, 0, 0, 0);
        f32x4 Dz1a = __builtin_amdgcn_mfma_f32_16x16x32_f16(a1a, bz[1], z4, 0, 0, 0);
        f32x4 Dt0a = __builtin_amdgcn_mfma_f32_16x16x32_f16(a1a, bt[0], z4, 0, 0, 0);
        f32x4 Dt1a = __builtin_amdgcn_mfma_f32_16x16x32_f16(a1a, bt[1], z4, 0, 0, 0);
        f32x4 Dz0b = __builtin_amdgcn_mfma_f32_16x16x32_f16(a1b, bz[0], z4, 0, 0, 0);
        f32x4 Dz1b = __builtin_amdgcn_mfma_f32_16x16x32_f16(a1b, bz[1], z4, 0, 0, 0);
        f32x4 Dt0b = __builtin_amdgcn_mfma_f32_16x16x32_f16(a1b, bt[0], z4, 0, 0, 0);
        f32x4 Dt1b = __builtin_amdgcn_mfma_f32_16x16x32_f16(a1b, bt[1], z4, 0, 0, 0);
        const int f0 = lane & 15, e0 = (lane >> 4) * 4;
        const float bb0 = br1[f0], bb1 = br1[16 + f0];
        #pragma unroll
        for (int tl = 0; tl < 2; tl++) {
            #pragma unroll
            for (int t = 0; t < 2; t++) {
                f32x4 Dz = tl ? (t ? Dz1b : Dz0b) : (t ? Dz1a : Dz0a);
                f32x4 Dt = tl ? (t ? Dt1b : Dt0b) : (t ? Dt1a : Dt0a);
                float bb = t ? bb1 : bb0;
                #pragma unroll
                for (int r = 0; r < 4; r++) {
                    float z = Dz[r] + bb;
                    float sg = sigmoidf_(z);
                    sW[w][1280 + tl * 640 + (e0 + r) * QP + t * 16 + f0] = (_Float16)(z * sg);
                    sW[w][2560 + tl * 640 + (e0 + r) * QP + t * 16 + f0] =
                        (_Float16)((sg * (1.0f + z * (1.0f - sg))) * Dt[r]);
                }
            }
        }
    }

    // ---- phase 2: 16 MFMAs; fold hs; interleaved (q,t) uint4 stores ----
    {
        const int me = lane & 15;
        f16x8 aqa = *(const f16x8*)&sW[w][1280 + me * QP + kb];
        f16x8 aqb = *(const f16x8*)&sW[w][1920 + me * QP + kb];
        f16x8 ata = *(const f16x8*)&sW[w][2560 + me * QP + kb];
        f16x8 atb = *(const f16x8*)&sW[w][3200 + me * QP + kb];
        const int cb = lane & 15, e0 = (lane >> 4) * 4;
        float hsv[2][2][4];   // [tile][fpair][r]
        #pragma unroll
        for (int tl = 0; tl < 2; tl++)
            #pragma unroll
            for (int r = 0; r < 4; r++) {
                int ty = sTy[w][tl * 16 + e0 + r];
                hsv[tl][0][r] = sTemb[ty * 32 + cb];
                hsv[tl][1][r] = sTemb[ty * 32 + 16 + cb];
            }
        const f32x4 z4 = {0.f, 0.f, 0.f, 0.f};
        unsigned int* Du = (unsigned int*)&sW[w][0];
        #pragma unroll
        for (int fp = 0; fp < 2; fp++) {
            f32x4 q0a = __builtin_amdgcn_mfma_f32_16x16x32_f16(aqa, bf[fp],     z4, 0, 0, 0);
            f32x4 q1a = __builtin_amdgcn_mfma_f32_16x16x32_f16(aqa, bf[fp + 2], z4, 0, 0, 0);
            f32x4 q0b = __builtin_amdgcn_mfma_f32_16x16x32_f16(aqb, bf[fp],     z4, 0, 0, 0);
            f32x4 q1b = __builtin_amdgcn_mfma_f32_16x16x32_f16(aqb, bf[fp + 2], z4, 0, 0, 0);
            f32x4 t0a = __builtin_amdgcn_mfma_f32_16x16x32_f16(ata, bf[fp],     z4, 0, 0, 0);
            f32x4 t1a = __builtin_amdgcn_mfma_f32_16x16x32_f16(ata, bf[fp + 2], z4, 0, 0, 0);
            f32x4 t0b = __builtin_amdgcn_mfma_f32_16x16x32_f16(atb, bf[fp],     z4, 0, 0, 0);
            f32x4 t1b = __builtin_amdgcn_mfma_f32_16x16x32_f16(atb, bf[fp + 2], z4, 0, 0, 0);
            const int f = fp * 16 + cb;
            {
                unsigned int pq[4], pt[4];
                #pragma unroll
                for (int r = 0; r < 4; r++) {
                    float h = hsv[0][fp][r];
                    pq[r] = pk2_(q0a[r] * h, q1a[r] * h);
                    pt[r] = pk2_(t0a[r] * h, t1a[r] * h);
                }
                *(uint4*)&Du[(f * DS2 + e0) * 2]     = make_uint4(pq[0], pt[0], pq[1], pt[1]);
                *(uint4*)&Du[(f * DS2 + e0 + 2) * 2] = make_uint4(pq[2], pt[2], pq[3], pt[3]);
            }
            {
                unsigned int pq[4], pt[4];
                #pragma unroll
                for (int r = 0; r < 4; r++) {
                    float h = hsv[1][fp][r];
                    pq[r] = pk2_(q0b[r] * h, q1b[r] * h);
                    pt[r] = pk2_(t0b[r] * h, t1b[r] * h);
                }
                *(uint4*)&Du[(f * DS2 + 16 + e0) * 2]     = make_uint4(pq[0], pt[0], pq[1], pt[1]);
                *(uint4*)&Du[(f * DS2 + 16 + e0 + 2) * 2] = make_uint4(pq[2], pt[2], pq[3], pt[3]);
            }
        }
    }

    // ---- phase 3: epilogue; 2 lanes per edge (f split in 2), 1-step reduce ----
    {
        const unsigned int* Du = (const unsigned int*)&sW[w][0];
        float Aa = 0.f, Bb = 0.f, Cc = 0.f, Pp = 0.f;
        float Ap = 0.f, Bp = 0.f, Cp = 0.f, Qq = 0.f;
        #pragma unroll
        for (int ff = 0; ff < 16; ff++) {
            const int f = fg * 16 + ff;
            uint2 qt = *(const uint2*)&Du[(f * DS2 + el) * 2];
            float rw0 = lo16_(qt.x), rw1 = hi16_(qt.x);
            float u0 = lo16_(qt.y), u1 = hi16_(qt.y);
            float4 g4 = (ff < 8) ? gg[ff] : *(const float4*)(gb + f * 4);
            Pp += rw0 * g4.x; Qq += u0 * g4.x;
            Aa += rw1 * g4.y; Bb += rw1 * g4.z; Cc += rw1 * g4.w;
            Ap += u1 * g4.y;  Bp += u1 * g4.z;  Cp += u1 * g4.w;
        }
        Pp += __shfl_xor(Pp, 32, 64); Qq += __shfl_xor(Qq, 32, 64);
        Aa += __shfl_xor(Aa, 32, 64); Bb += __shfl_xor(Bb, 32, 64);
        Cc += __shfl_xor(Cc, 32, 64); Ap += __shfl_xor(Ap, 32, 64);
        Bp += __shfl_xor(Bp, 32, 64); Cp += __shfl_xor(Cp, 32, 64);

        if (lane < 32) {
            float Gx = env * Aa, Gy = env * Bb, Gz = env * Cc;
            float genv = Pp + rhx * Aa + rhy * Bb + rhz * Cc;
            float pc = env * (Qq + rhx * Ap + rhy * Bp + rhz * Cp) + genv * denv;
            float dotg = Gx * rhx + Gy * rhy + Gz * rhz;
            float cx = pc * rhx + (Gx - dotg * rhx) * rinv;
            float cy = pc * rhy + (Gy - dotg * rhy) * rinv;
            float cz = pc * rhz + (Gz - dotg * rhz) * rinv;

            const float SC = EV2KJ_C * NM2A_C;
            if (valid) fbuf[p_e] = make_float4(SC * cx, SC * cy, SC * cz, 0.0f);

            int kk = key;
            #pragma unroll
            for (int d = 1; d < 32; d <<= 1) {
                float ux = __shfl_up(cx, d, 32);
                float uy = __shfl_up(cy, d, 32);
                float uz = __shfl_up(cz, d, 32);
                int uk = __shfl_up(kk, d, 32);
                if (el >= d && uk == kk) { cx += ux; cy += uy; cz += uz; }
            }
            int nk = __shfl_down(kk, 1, 32);
            bool leader = (el == 31) || (nk != kk);
            if (valid && leader) {
                unsafeAtomicAdd(&forces[(size_t)dstI * 3 + 0], -SC * cx);
                unsafeAtomicAdd(&forces[(size_t)dstI * 3 + 1], -SC * cy);
                unsafeAtomicAdd(&forces[(size_t)dstI * 3 + 2], -SC * cz);
            }
        }
    }
}

// ------- src gather via src-bins: LDS per-atom accumulation, few contiguous atomics -------
__global__ __launch_bounds__(256) void gather_src(
    float* __restrict__ forces, const int* __restrict__ sbbase,
    const int2* __restrict__ srcbin, const float4* __restrict__ fbuf,
    int ssh, int N)
{
    __shared__ float acc[3072];   // 1024 atoms x 3
    const int wg = blockIdx.x;
    const int b = wg / GSPLIT, part = wg % GSPLIT;
    const int base = sbbase[b];
    const int cnt = sbbase[b + 1] - base;
    const int r0 = base + (int)((long long)cnt * part / GSPLIT);
    const int r1 = base + (int)((long long)cnt * (part + 1) / GSPLIT);
    const int abase = b << ssh;
    const bool lok = (ssh <= 10);
    for (int i = threadIdx.x; i < 3072; i += 256) acc[i] = 0.f;
    __syncthreads();
    for (int i = r0 + threadIdx.x; i < r1; i += 256) {
        int2 r = srcbin[i];
        float4 f = fbuf[r.y];
        if (lok) {
            int la = r.x - abase;
            atomicAdd(&acc[la * 3 + 0], f.x);
            atomicAdd(&acc[la * 3 + 1], f.y);
            atomicAdd(&acc[la * 3 + 2], f.z);
        } else {
            unsafeAtomicAdd(&forces[(size_t)r.x * 3 + 0], f.x);
            unsafeAtomicAdd(&forces[(size_t)r.x * 3 + 1], f.y);
            unsafeAtomicAdd(&forces[(size_t)r.x * 3 + 2], f.z);
        }
    }
    __syncthreads();
    if (lok) {
        for (int la = threadIdx.x; la < 1024; la += 256) {
            int a = abase + la;
            if (a < N) {
                float ax = acc[la * 3 + 0], ay = acc[la * 3 + 1], az = acc[la * 3 + 2];
                if (ax != 0.f || ay != 0.f || az != 0.f) {
                    unsafeAtomicAdd(&forces[(size_t)a * 3 + 0], ax);
                    unsafeAtomicAdd(&forces[(size_t)a * 3 + 1], ay);
                    unsafeAtomicAdd(&forces[(size_t)a * 3 + 2], az);
                }
            }
        }
    }
}

// ---------------- reductions & correction ----------------
__global__ __launch_bounds__(256) void reduce_net(
    const float* __restrict__ f, const float* __restrict__ masses,
    float* __restrict__ accum, int N)
{
    float nx = 0, ny = 0, nz = 0, ms = 0;
    for (int i = blockIdx.x * 256 + threadIdx.x; i < N; i += gridDim.x * 256) {
        nx += f[i * 3 + 0]; ny += f[i * 3 + 1]; nz += f[i * 3 + 2]; ms += masses[i];
    }
    #pragma unroll
    for (int m = 32; m; m >>= 1) {
        nx += __shfl_xor(nx, m, 64);
        ny += __shfl_xor(ny, m, 64);
        nz += __shfl_xor(nz, m, 64);
        ms += __shfl_xor(ms, m, 64);
    }
    __shared__ float red[4][4];
    int w = threadIdx.x >> 6;
    if ((threadIdx.x & 63) == 0) { red[w][0] = nx; red[w][1] = ny; red[w][2] = nz; red[w][3] = ms; }
    __syncthreads();
    if (threadIdx.x == 0) {
        float a0 = 0, a1 = 0, a2 = 0, a3 = 0;
        for (int i = 0; i < 4; i++) { a0 += red[i][0]; a1 += red[i][1]; a2 += red[i][2]; a3 += red[i][3]; }
        unsafeAtomicAdd(accum + 0, a0);
        unsafeAtomicAdd(accum + 1, a1);
        unsafeAtomicAdd(accum + 2, a2);
        unsafeAtomicAdd(accum + 3, a3);
    }
}

__global__ __launch_bounds__(256) void correct_forces(
    float* __restrict__ f, const float* __restrict__ masses,
    const float* __restrict__ accum, int N)
{
    int i = blockIdx.x * 256 + threadIdx.x;
    if (i < N) {
        float c = masses[i] / accum[3];
        f[i * 3 + 0] -= c * accum[0];
        f[i * 3 + 1] -= c * accum[1];
        f[i * 3 + 2] -= c * accum[2];
    }
}

extern "C" void kernel_launch(void* const* d_in, const int* in_sizes, int n_in,
                              void* d_out, int out_size, void* d_ws, size_t ws_size,
                              hipStream_t stream)
{
    (void)n_in; (void)ws_size;
    const float* pos    = (const float*)d_in[0];
    const float* masses = (const float*)d_in[1];
    const float* temb   = (const float*)d_in[2];
    const float* Wr1    = (const float*)d_in[3];
    const float* br1    = (const float*)d_in[4];
    const float* Wr2    = (const float*)d_in[5];
    const float* Wself  = (const float*)d_in[6];
    const float* Wo1    = (const float*)d_in[7];
    const float* bo1    = (const float*)d_in[8];
    const float* Wo2    = (const float*)d_in[9];
    const int* types    = (const int*)d_in[10];
    const int* eidx     = (const int*)d_in[11];
    const int N = in_sizes[1];
    const int E = in_sizes[11] / 2;

    float* out = (float*)d_out;
    float* forces = out + 1;

    // bucket geometry (dst buckets <=512, src buckets <=64)
    int dsh = 7;  while (((N + (1 << dsh) - 1) >> dsh) > 512) dsh++;
    int nbd = (N + (1 << dsh) - 1) >> dsh;
    int ssh = 10; while (((N + (1 << ssh) - 1) >> ssh) > 64) ssh++;
    int nbs = (N + (1 << ssh) - 1) >> ssh;

    float* ws = (float*)d_ws;
    float* s_acc = ws;                               // N*32
    float* v_acc = s_acc + (size_t)N * FDIM;         // N*96
    float* g_all = v_acc + (size_t)N * 96;           // N*128
    float* accum = g_all + (size_t)N * 128;          // 4
    int* meta = (int*)(accum + 4);
    int* dbcnt  = meta;                              // 512
    int* sbcnt  = dbcnt + 512;                       // 64
    int* dbcur  = sbcnt + 64;                        // 512
    int* sbcur  = dbcur + 512;                       // 64
    int* dbbase = sbcur + 64;                        // 513
    int* sbbase = dbbase + 513;                      // 65
    int2* order_sd = (int2*)(((uintptr_t)(sbbase + 65) + 15) & ~(uintptr_t)15);  // E
    int2* srcbin   = order_sd + E;                                               // E
    float4* fbuf   = (float4*)(((uintptr_t)(srcbin + E) + 15) & ~(uintptr_t)15); // E
    _Float16* wpack = (_Float16*)(fbuf + E);                                     // 8KB

    hipMemsetAsync(d_out, 0, (size_t)out_size * sizeof(float), stream);
    hipMemsetAsync(s_acc, 0, (size_t)N * 128 * sizeof(float), stream);
    hipMemsetAsync(meta, 0, 1152 * sizeof(int), stream);   // dbcnt|sbcnt|dbcur|sbcur
    hipMemsetAsync(accum, 0, 4 * sizeof(float), stream);

    hist_buckets<<<512, 256, 0, stream>>>(eidx, dbcnt, sbcnt, E, dsh, ssh, nbd, nbs);
    scan_bases<<<1, 512, 0, stream>>>(dbcnt, sbcnt, dbbase, sbbase, nbd, nbs);
    int nBin = (E + BINW - 1) / BINW;
    bin_dst<<<nBin, 256, 0, stream>>>(eidx, dbbase, dbcur, order_sd, E, dsh, nbd);
    sort_bucket<<<nbd, 256, 0, stream>>>(order_sd, dbbase, sbcur, sbbase, srcbin, dsh, ssh);
    pack_wfrag<<<1, 64, 0, stream>>>(Wr1, Wr2, wpack);

    int nAtomBlocks = (N + 63) / 64;
    int nFwdBlocks = (E + 127) / 128;
    int nBwdBlocks = (E + 127) / 128;
    edge_fwd_mfma<<<nFwdBlocks, 256, 0, stream>>>(pos, types, order_sd,
                                                  wpack, br1, temb,
                                                  s_acc, v_acc, E);
    atom_mlp<<<nAtomBlocks, 64, 0, stream>>>(types, temb, Wself, Wo1, bo1, Wo2,
                                             s_acc, v_acc, g_all, out, N);
    edge_bwd_mfma<<<nBwdBlocks, 256, 0, stream>>>(pos, types, order_sd,
                                                  wpack, br1, temb,
                                                  g_all, forces, fbuf, E);
    gather_src<<<nbs * GSPLIT, 256, 0, stream>>>(forces, sbbase, srcbin, fbuf, ssh, N);
    reduce_net<<<64, 256, 0, stream>>>(forces, masses, accum, N);
    correct_forces<<<(N + 255) / 256, 256, 0, stream>>>(forces, masses, accum, N);
}